// Round 5
// baseline (846.700 us; speedup 1.0000x reference)
//
#include <hip/hip_runtime.h>
#include <hip/hip_cooperative_groups.h>
#include <math.h>

namespace cg = cooperative_groups;

#define NN 1024
#define HID 64
#define HEADD 128
#define NODE_DIM 14
#define BATCH 32
#define CAP 64
#define ROWS (BATCH * NN)     // 32768
#define RPW 8                 // rows per chunk (one wave owns a chunk)
#define NCHUNK (ROWS / RPW)   // 4096

// One SpMM row: acc[lane] = sum_k dv_k * g_in[j_k][lane], gather unrolled x4
// so 4 independent loads are in flight per s_waitcnt.
__device__ __forceinline__ float spmm_row(const float* __restrict__ g_in,
                                          int bbase, int n, int idx, float dv,
                                          int lane) {
    float acc = 0.f;
    int k = 0;
    for (; k + 4 <= n; k += 4) {
        int j0 = __shfl(idx, k),     j1 = __shfl(idx, k + 1);
        int j2 = __shfl(idx, k + 2), j3 = __shfl(idx, k + 3);
        float w0 = __shfl(dv, k),     w1 = __shfl(dv, k + 1);
        float w2 = __shfl(dv, k + 2), w3 = __shfl(dv, k + 3);
        float v0 = g_in[(size_t)(bbase + j0) * HID + lane];
        float v1 = g_in[(size_t)(bbase + j1) * HID + lane];
        float v2 = g_in[(size_t)(bbase + j2) * HID + lane];
        float v3 = g_in[(size_t)(bbase + j3) * HID + lane];
        acc += w0 * v0; acc += w1 * v1; acc += w2 * v2; acc += w3 * v3;
    }
    for (; k < n; ++k) {
        int j = __shfl(idx, k);
        float w = __shfl(dv, k);
        acc += w * g_in[(size_t)(bbase + j) * HID + lane];
    }
    return acc;
}

__global__ __launch_bounds__(256, 2) void k_fused(
    const float* __restrict__ x, const float* __restrict__ adj,
    const float* __restrict__ W1, const float* __restrict__ b1,
    const float* __restrict__ W2, const float* __restrict__ b2,
    const float* __restrict__ W3, const float* __restrict__ b3,
    const float* __restrict__ Wf1, const float* __restrict__ bf1,
    const float* __restrict__ Wf2, const float* __restrict__ bf2,
    int* __restrict__ csr, int* __restrict__ nnz_g, float* __restrict__ dinv,
    float* __restrict__ pooled, float* __restrict__ g1, float* __restrict__ g2,
    float* __restrict__ g3, float* __restrict__ out) {
    cg::grid_group grid = cg::this_grid();
    __shared__ float sW1[NODE_DIM * HID];   // 3.5 KB
    __shared__ float sWb[HID * HID];        // 16 KB (W2, then W3)
    __shared__ float sred[4][HID];          // 1 KB
    __shared__ float shead[HEADD];          // 0.5 KB
    int t = threadIdx.x, wv = t >> 6, lane = t & 63;
    int blk = blockIdx.x;
    int w = blk * 4 + wv;                   // wave id
    int nw = gridDim.x * 4;                 // total waves (4096 % nw == 0)

    for (int i = t; i < NODE_DIM * HID; i += 256) sW1[i] = W1[i];
    for (int i = t; i < HID * HID; i += 256) sWb[i] = W2[i];
    if (blk < 8) pooled[blk * 256 + t] = 0.f;   // zero 2048-float accumulator
    __syncthreads();

    // ---- Phase 1: CSR build (ballot compaction) + g1 = x @ W1 ----
    for (int c = w; c < NCHUNK; c += nw) {
        int row0 = c * RPW;
        for (int r = 0; r < RPW; ++r) {
            int row = row0 + r;
            const float4* rp = reinterpret_cast<const float4*>(adj + (size_t)row * NN);
            unsigned long long lt = ((unsigned long long)1 << lane) - 1;
            int base = 0;
#pragma unroll
            for (int j = 0; j < 4; ++j) {
                float4 v = rp[lane + 64 * j];
                float vv[4] = {v.x, v.y, v.z, v.w};
#pragma unroll
                for (int k = 0; k < 4; ++k) {
                    unsigned long long mk = __ballot(vv[k] != 0.0f);
                    if (vv[k] != 0.0f) {
                        int pos = base + __popcll(mk & lt);
                        if (pos < CAP) csr[row * CAP + pos] = (lane + 64 * j) * 4 + k;
                    }
                    base += __popcll(mk);
                }
            }
            if (lane == 0) {
                nnz_g[row] = base < CAP ? base : CAP;
                dinv[row] = 1.0f / sqrtf((float)(base < 1 ? 1 : base));
            }
            float acc = 0.f;
            const float* xr = x + (size_t)row * NODE_DIM;
#pragma unroll
            for (int d = 0; d < NODE_DIM; ++d) acc += xr[d] * sW1[d * HID + lane];
            g1[(size_t)row * HID + lane] = acc;
        }
    }
    __threadfence();
    grid.sync();

    // ---- Phase 2: g2 = relu(DAD g1 + b1) @ W2 ----
    for (int c = w; c < NCHUNK; c += nw) {
        int row0 = c * RPW, bbase = row0 & ~(NN - 1);
        float bb = b1[lane];
        float h[RPW], o[RPW];
#pragma unroll
        for (int r = 0; r < RPW; ++r) {
            int row = row0 + r;
            int n = nnz_g[row];
            int idx = (lane < n) ? csr[row * CAP + lane] : 0;
            float dv = (lane < n) ? dinv[bbase + idx] : 0.f;
            h[r] = fmaxf(dinv[row] * spmm_row(g1, bbase, n, idx, dv, lane) + bb, 0.f);
            o[r] = 0.f;
        }
        for (int d = 0; d < HID; ++d) {
            float wgt = sWb[d * HID + lane];
#pragma unroll
            for (int r = 0; r < RPW; ++r) o[r] += __shfl(h[r], d) * wgt;
        }
#pragma unroll
        for (int r = 0; r < RPW; ++r)
            g2[(size_t)(row0 + r) * HID + lane] = o[r];
    }
    __threadfence();
    grid.sync();

    // swap weight buffer to W3
    for (int i = t; i < HID * HID; i += 256) sWb[i] = W3[i];
    __syncthreads();

    // ---- Phase 3: g3 = relu(DAD g2 + b2) @ W3 ----
    for (int c = w; c < NCHUNK; c += nw) {
        int row0 = c * RPW, bbase = row0 & ~(NN - 1);
        float bb = b2[lane];
        float h[RPW], o[RPW];
#pragma unroll
        for (int r = 0; r < RPW; ++r) {
            int row = row0 + r;
            int n = nnz_g[row];
            int idx = (lane < n) ? csr[row * CAP + lane] : 0;
            float dv = (lane < n) ? dinv[bbase + idx] : 0.f;
            h[r] = fmaxf(dinv[row] * spmm_row(g2, bbase, n, idx, dv, lane) + bb, 0.f);
            o[r] = 0.f;
        }
        for (int d = 0; d < HID; ++d) {
            float wgt = sWb[d * HID + lane];
#pragma unroll
            for (int r = 0; r < RPW; ++r) o[r] += __shfl(h[r], d) * wgt;
        }
#pragma unroll
        for (int r = 0; r < RPW; ++r)
            g3[(size_t)(row0 + r) * HID + lane] = o[r];
    }
    __threadfence();
    grid.sync();

    // ---- Phase 4: h3 = relu(DAD g3 + b3); block-pool + atomic ----
    // Block's 4 waves handle 4 consecutive chunks = 32 rows = one batch slice.
    for (int c = w; c < NCHUNK; c += nw) {
        int row0 = c * RPW, bbase = row0 & ~(NN - 1);
        float bb = b3[lane];
        float s = 0.f;
#pragma unroll
        for (int r = 0; r < RPW; ++r) {
            int row = row0 + r;
            int n = nnz_g[row];
            int idx = (lane < n) ? csr[row * CAP + lane] : 0;
            float dv = (lane < n) ? dinv[bbase + idx] : 0.f;
            s += fmaxf(dinv[row] * spmm_row(g3, bbase, n, idx, dv, lane) + bb, 0.f);
        }
        sred[wv][lane] = s;
        __syncthreads();
        if (wv == 0) {
            float tot = sred[0][lane] + sred[1][lane] + sred[2][lane] + sred[3][lane];
            atomicAdd(&pooled[(row0 >> 10) * HID + lane], tot);
        }
        __syncthreads();
    }
    __threadfence();
    grid.sync();

    // ---- Phase 5: head (blocks 0..31, one per batch) ----
    if (blk < BATCH) {
        if (t < HID) sred[0][t] = pooled[blk * HID + t] * (1.0f / NN);
        __syncthreads();
        if (t < HEADD) {
            float a = bf1[t];
            for (int d = 0; d < HID; ++d) a += sred[0][d] * Wf1[d * HEADD + t];
            shead[t] = fmaxf(a, 0.f);
        }
        __syncthreads();
        if (t < 64) {
            float v = shead[t] * Wf2[t] + shead[t + 64] * Wf2[t + 64];
#pragma unroll
            for (int off = 32; off > 0; off >>= 1) v += __shfl_down(v, off, 64);
            if (t == 0) out[blk] = v + bf2[0];
        }
    }
}

extern "C" void kernel_launch(void* const* d_in, const int* in_sizes, int n_in,
                              void* d_out, int out_size, void* d_ws, size_t ws_size,
                              hipStream_t stream) {
    const float* x   = (const float*)d_in[0];
    const float* adj = (const float*)d_in[1];
    const float* W1  = (const float*)d_in[2];
    const float* b1  = (const float*)d_in[3];
    const float* W2  = (const float*)d_in[4];
    const float* b2  = (const float*)d_in[5];
    const float* W3  = (const float*)d_in[6];
    const float* b3  = (const float*)d_in[7];
    const float* Wf1 = (const float*)d_in[8];
    const float* bf1 = (const float*)d_in[9];
    const float* Wf2 = (const float*)d_in[10];
    const float* bf2 = (const float*)d_in[11];
    float* out = (float*)d_out;

    // workspace carve: csr 8MB | nnz 128KB | dinv 128KB | pooled 16KB | g1,g2,g3 8MB each
    char* ws = (char*)d_ws;
    int*   csr    = (int*)ws;
    int*   nnz_g  = (int*)(ws + (size_t)ROWS * CAP * 4);
    float* dinv   = (float*)(ws + (size_t)ROWS * CAP * 4 + (size_t)ROWS * 4);
    float* pooled = (float*)(ws + (size_t)ROWS * CAP * 4 + (size_t)2 * ROWS * 4);
    float* g1     = (float*)(ws + (size_t)ROWS * CAP * 4 + (size_t)2 * ROWS * 4 + 4096 * 4);
    float* g2     = g1 + (size_t)ROWS * HID;
    float* g3     = g2 + (size_t)ROWS * HID;

    // Cooperative-capacity-safe grid: query actual occupancy, floor to a
    // power of two (so 4*G divides 4096 -> uniform phase iteration counts).
    int maxBlkPerCU = 0;
    (void)hipOccupancyMaxActiveBlocksPerMultiprocessor(&maxBlkPerCU, k_fused, 256, 0);
    int maxCoop = maxBlkPerCU * 256;        // 256 CUs on MI355X
    int G = 1024;
    while (G > maxCoop && G > 32) G >>= 1;  // never exceed co-resident capacity

    void* args[] = {(void*)&x,  (void*)&adj, (void*)&W1,  (void*)&b1,
                    (void*)&W2,  (void*)&b2,  (void*)&W3,  (void*)&b3,
                    (void*)&Wf1, (void*)&bf1, (void*)&Wf2, (void*)&bf2,
                    (void*)&csr, (void*)&nnz_g, (void*)&dinv, (void*)&pooled,
                    (void*)&g1,  (void*)&g2,  (void*)&g3,  (void*)&out};
    hipLaunchCooperativeKernel((const void*)k_fused, dim3(G), dim3(256),
                               args, 0, stream);
}

// Round 6
// 342.547 us; speedup vs baseline: 2.4718x; 2.4718x over previous
//
#include <hip/hip_runtime.h>
#include <math.h>

#define NN 1024
#define HID 64
#define HEADD 128
#define NODE_DIM 14
#define BATCH 32
#define CAP 64
#define ROWS (BATCH * NN)   // 32768

// XCD-aware row mapping: blocks with blockIdx%8==x land on XCD x (dispatch
// round-robin heuristic). All 1024 rows of a batch map to one XCD class, so
// that batch's 256KB gather slab stays resident in that XCD's 4MB L2.
// blk in [0,8192): x=blk&7, q=blk>>3; batch = x + 8*(q>>8); node0 = (q&255)*4.
// Each of the block's 4 waves owns row = batch*NN + node0 + wv.
__device__ __forceinline__ int swizzle_row(int blk, int wv) {
    int x = blk & 7, q = blk >> 3;
    int batch = x + 8 * (q >> 8);
    int node = ((q & 255) << 2) + wv;
    return batch * NN + node;
}

// ---------------- K1: CSR build (ballot) + g1 = x @ W1 + zero pooled --------
__global__ __launch_bounds__(256) void k_build(const float* __restrict__ adj,
                                               const float* __restrict__ x,
                                               const float* __restrict__ W1,
                                               int* __restrict__ csr,
                                               int* __restrict__ nnz_g,
                                               float* __restrict__ dinv,
                                               float* __restrict__ g1,
                                               float* __restrict__ pooled) {
    __shared__ float sW1[NODE_DIM * HID];
    for (int i = threadIdx.x; i < NODE_DIM * HID; i += 256) sW1[i] = W1[i];
    if (blockIdx.x < 8) pooled[blockIdx.x * 256 + threadIdx.x] = 0.f;
    int wv = threadIdx.x >> 6, lane = threadIdx.x & 63;
    int row = swizzle_row(blockIdx.x, wv);
    const float4* rp = reinterpret_cast<const float4*>(adj + (size_t)row * NN);
    unsigned long long lt = ((unsigned long long)1 << lane) - 1;
    int base = 0;
#pragma unroll
    for (int j = 0; j < 4; ++j) {
        float4 v = rp[lane + 64 * j];
        float vv[4] = {v.x, v.y, v.z, v.w};
#pragma unroll
        for (int k = 0; k < 4; ++k) {
            unsigned long long mk = __ballot(vv[k] != 0.0f);
            if (vv[k] != 0.0f) {
                int pos = base + __popcll(mk & lt);
                if (pos < CAP) csr[row * CAP + pos] = (lane + 64 * j) * 4 + k;
            }
            base += __popcll(mk);
        }
    }
    if (lane == 0) {
        nnz_g[row] = base < CAP ? base : CAP;
        dinv[row] = 1.0f / sqrtf((float)(base < 1 ? 1 : base));
    }
    __syncthreads();                                 // sW1 ready
    float acc = 0.f;
    const float* xr = x + (size_t)row * NODE_DIM;
#pragma unroll
    for (int d = 0; d < NODE_DIM; ++d) acc += xr[d] * sW1[d * HID + lane];
    g1[(size_t)row * HID + lane] = acc;
}

// Gather-SpMM for one row, 8/4/1-wide unrolled so up to 8 loads in flight.
__device__ __forceinline__ float spmm_row(const float* __restrict__ g_in,
                                          int bbase, int n, int idx, float dv,
                                          int lane) {
    float acc = 0.f;
    int k = 0;
    for (; k + 8 <= n; k += 8) {
        int j[8]; float w[8], v[8];
#pragma unroll
        for (int u = 0; u < 8; ++u) { j[u] = __shfl(idx, k + u); w[u] = __shfl(dv, k + u); }
#pragma unroll
        for (int u = 0; u < 8; ++u) v[u] = g_in[(size_t)(bbase + j[u]) * HID + lane];
#pragma unroll
        for (int u = 0; u < 8; ++u) acc += w[u] * v[u];
    }
    for (; k + 4 <= n; k += 4) {
        int j[4]; float w[4], v[4];
#pragma unroll
        for (int u = 0; u < 4; ++u) { j[u] = __shfl(idx, k + u); w[u] = __shfl(dv, k + u); }
#pragma unroll
        for (int u = 0; u < 4; ++u) v[u] = g_in[(size_t)(bbase + j[u]) * HID + lane];
#pragma unroll
        for (int u = 0; u < 4; ++u) acc += w[u] * v[u];
    }
    for (; k < n; ++k)
        acc += __shfl(dv, k) * g_in[(size_t)(bbase + __shfl(idx, k)) * HID + lane];
    return acc;
}

// ---------------- K2/K3: g_out = relu(D A D g_in + bias) @ W ----------------
__global__ __launch_bounds__(256) void k_layer(const float* __restrict__ g_in,
                                               const int* __restrict__ csr,
                                               const int* __restrict__ nnz_g,
                                               const float* __restrict__ dinv,
                                               const float* __restrict__ bias,
                                               const float* __restrict__ W,
                                               float* __restrict__ g_out) {
    __shared__ float sW[HID * HID];                  // 16 KB
    for (int i = threadIdx.x; i < HID * HID; i += 256) sW[i] = W[i];
    int wv = threadIdx.x >> 6, lane = threadIdx.x & 63;
    int row = swizzle_row(blockIdx.x, wv);
    int bbase = row & ~(NN - 1);
    int n = nnz_g[row];
    int idx = (lane < n) ? csr[row * CAP + lane] : 0;
    float dv = (lane < n) ? dinv[bbase + idx] : 0.f;
    float acc = spmm_row(g_in, bbase, n, idx, dv, lane);
    float h = fmaxf(dinv[row] * acc + bias[lane], 0.f);
    __syncthreads();                                 // sW ready
    float o = 0.f;
#pragma unroll 8
    for (int d = 0; d < HID; ++d)
        o += __shfl(h, d) * sW[d * HID + lane];
    g_out[(size_t)row * HID + lane] = o;
}

// ---------------- K4: h3 = relu(DAD g3 + b3); pool via atomics --------------
__global__ __launch_bounds__(256) void k_layer3(const float* __restrict__ g_in,
                                                const int* __restrict__ csr,
                                                const int* __restrict__ nnz_g,
                                                const float* __restrict__ dinv,
                                                const float* __restrict__ bias,
                                                float* __restrict__ pooled) {
    __shared__ float sred[4][HID];
    int wv = threadIdx.x >> 6, lane = threadIdx.x & 63;
    int row = swizzle_row(blockIdx.x, wv);
    int bbase = row & ~(NN - 1);
    int n = nnz_g[row];
    int idx = (lane < n) ? csr[row * CAP + lane] : 0;
    float dv = (lane < n) ? dinv[bbase + idx] : 0.f;
    float acc = spmm_row(g_in, bbase, n, idx, dv, lane);
    sred[wv][lane] = fmaxf(dinv[row] * acc + bias[lane], 0.f);
    __syncthreads();
    if (wv == 0) {
        float tot = sred[0][lane] + sred[1][lane] + sred[2][lane] + sred[3][lane];
        atomicAdd(&pooled[(bbase >> 10) * HID + lane], tot);   // 4 rows share batch
    }
}

// ---------------- K5: head: mean + relu(p@Wf1+bf1)@Wf2+bf2 ------------------
__global__ __launch_bounds__(128) void k_head(const float* __restrict__ pooled_sum,
                                              const float* __restrict__ Wf1,
                                              const float* __restrict__ bf1,
                                              const float* __restrict__ Wf2,
                                              const float* __restrict__ bf2,
                                              float* __restrict__ out) {
    int b = blockIdx.x, t = threadIdx.x;
    __shared__ float p[HID];
    __shared__ float hid[HEADD];
    if (t < HID) p[t] = pooled_sum[b * HID + t] * (1.0f / NN);
    __syncthreads();
    float acc = bf1[t];
    for (int d = 0; d < HID; ++d) acc += p[d] * Wf1[d * HEADD + t];
    hid[t] = fmaxf(acc, 0.f);
    __syncthreads();
    if (t < 64) {
        float v = hid[t] * Wf2[t] + hid[t + 64] * Wf2[t + 64];
#pragma unroll
        for (int off = 32; off > 0; off >>= 1) v += __shfl_down(v, off, 64);
        if (t == 0) out[b] = v + bf2[0];
    }
}

extern "C" void kernel_launch(void* const* d_in, const int* in_sizes, int n_in,
                              void* d_out, int out_size, void* d_ws, size_t ws_size,
                              hipStream_t stream) {
    const float* x   = (const float*)d_in[0];
    const float* adj = (const float*)d_in[1];
    const float* W1  = (const float*)d_in[2];
    const float* b1  = (const float*)d_in[3];
    const float* W2  = (const float*)d_in[4];
    const float* b2  = (const float*)d_in[5];
    const float* W3  = (const float*)d_in[6];
    const float* b3  = (const float*)d_in[7];
    const float* Wf1 = (const float*)d_in[8];
    const float* bf1 = (const float*)d_in[9];
    const float* Wf2 = (const float*)d_in[10];
    const float* bf2 = (const float*)d_in[11];
    float* out = (float*)d_out;

    // workspace carve: csr 8MB | nnz 128KB | dinv 128KB | pooled 16KB | g1,g2,g3 8MB each
    char* ws = (char*)d_ws;
    int*   csr    = (int*)ws;
    int*   nnz_g  = (int*)(ws + (size_t)ROWS * CAP * 4);
    float* dinv   = (float*)(ws + (size_t)ROWS * CAP * 4 + (size_t)ROWS * 4);
    float* pooled = (float*)(ws + (size_t)ROWS * CAP * 4 + (size_t)2 * ROWS * 4);
    float* g1     = (float*)(ws + (size_t)ROWS * CAP * 4 + (size_t)2 * ROWS * 4 + 4096 * 4);
    float* g2     = g1 + (size_t)ROWS * HID;
    float* g3     = g2 + (size_t)ROWS * HID;

    k_build <<<ROWS / 4, 256, 0, stream>>>(adj, x, W1, csr, nnz_g, dinv, g1, pooled);
    k_layer <<<ROWS / 4, 256, 0, stream>>>(g1, csr, nnz_g, dinv, b1, W2, g2);
    k_layer <<<ROWS / 4, 256, 0, stream>>>(g2, csr, nnz_g, dinv, b2, W3, g3);
    k_layer3<<<ROWS / 4, 256, 0, stream>>>(g3, csr, nnz_g, dinv, b3, pooled);
    k_head  <<<BATCH, 128, 0, stream>>>(pooled, Wf1, bf1, Wf2, bf2, out);
}

// Round 7
// 331.166 us; speedup vs baseline: 2.5567x; 1.0344x over previous
//
#include <hip/hip_runtime.h>
#include <math.h>

#define NN 1024
#define HID 64
#define HEADD 128
#define NODE_DIM 14
#define BATCH 32
#define CAP 64
#define ROWS (BATCH * NN)   // 32768
#define RPW 8               // rows per wave in layer kernels

// ---- swizzles -------------------------------------------------------------
// k_build: 8192 blocks, 4 rows/block. blk%8 selects XCD class; batch b uses
// blocks with blk%8 == b%8 so its slab stays in one XCD's L2.
__device__ __forceinline__ int swz4(int blk, int wv) {
    int x = blk & 7, q = blk >> 3;
    int batch = x + 8 * (q >> 8);
    return batch * NN + ((q & 255) << 2) + wv;
}
// layer kernels: 1024 blocks, 32 rows/block (4 waves x 8 rows), same XCD rule.
__device__ __forceinline__ int swz32(int blk, int wv) {
    int x = blk & 7, q = blk >> 3;          // q in [0,128)
    int batch = x + 8 * (q >> 5);           // q>>5 in [0,4)
    return batch * NN + ((q & 31) << 5) + wv * RPW;
}

// ---------------- K1: CSR build (ballot) + g1 = x @ W1 + zero pooled --------
__global__ __launch_bounds__(256) void k_build(const float* __restrict__ adj,
                                               const float* __restrict__ x,
                                               const float* __restrict__ W1,
                                               int* __restrict__ csr,
                                               int* __restrict__ nnz_g,
                                               float* __restrict__ dinv,
                                               float* __restrict__ g1,
                                               float* __restrict__ pooled) {
    __shared__ float sW1[NODE_DIM * HID];
    for (int i = threadIdx.x; i < NODE_DIM * HID; i += 256) sW1[i] = W1[i];
    if (blockIdx.x < 8) pooled[blockIdx.x * 256 + threadIdx.x] = 0.f;
    int wv = threadIdx.x >> 6, lane = threadIdx.x & 63;
    int row = swz4(blockIdx.x, wv);
    const float4* rp = reinterpret_cast<const float4*>(adj + (size_t)row * NN);
    unsigned long long lt = ((unsigned long long)1 << lane) - 1;
    int base = 0;
#pragma unroll
    for (int j = 0; j < 4; ++j) {
        float4 v = rp[lane + 64 * j];
        float vv[4] = {v.x, v.y, v.z, v.w};
#pragma unroll
        for (int k = 0; k < 4; ++k) {
            unsigned long long mk = __ballot(vv[k] != 0.0f);
            if (vv[k] != 0.0f) {
                int pos = base + __popcll(mk & lt);
                if (pos < CAP) csr[row * CAP + pos] = (lane + 64 * j) * 4 + k;
            }
            base += __popcll(mk);
        }
    }
    if (lane == 0) {
        nnz_g[row] = base < CAP ? base : CAP;
        dinv[row] = 1.0f / sqrtf((float)(base < 1 ? 1 : base));
    }
    __syncthreads();
    float acc = 0.f;
    const float* xr = x + (size_t)row * NODE_DIM;
#pragma unroll
    for (int d = 0; d < NODE_DIM; ++d) acc += xr[d] * sW1[d * HID + lane];
    g1[(size_t)row * HID + lane] = acc;
}

// Gather-SpMM for one row, 8/4/1-wide unrolled (up to 8 loads in flight).
__device__ __forceinline__ float spmm_row(const float* __restrict__ g_in,
                                          int bbase, int n, int idx, float dv,
                                          int lane) {
    float acc = 0.f;
    int k = 0;
    for (; k + 8 <= n; k += 8) {
        int j[8]; float w[8], v[8];
#pragma unroll
        for (int u = 0; u < 8; ++u) { j[u] = __shfl(idx, k + u); w[u] = __shfl(dv, k + u); }
#pragma unroll
        for (int u = 0; u < 8; ++u) v[u] = g_in[(size_t)(bbase + j[u]) * HID + lane];
#pragma unroll
        for (int u = 0; u < 8; ++u) acc += w[u] * v[u];
    }
    for (; k + 4 <= n; k += 4) {
        int j[4]; float w[4], v[4];
#pragma unroll
        for (int u = 0; u < 4; ++u) { j[u] = __shfl(idx, k + u); w[u] = __shfl(dv, k + u); }
#pragma unroll
        for (int u = 0; u < 4; ++u) v[u] = g_in[(size_t)(bbase + j[u]) * HID + lane];
#pragma unroll
        for (int u = 0; u < 4; ++u) acc += w[u] * v[u];
    }
    for (; k < n; ++k)
        acc += __shfl(dv, k) * g_in[(size_t)(bbase + __shfl(idx, k)) * HID + lane];
    return acc;
}

// ---------------- K2: layer1 — gathers dinv, EMITS packed edges -------------
__global__ __launch_bounds__(256) void k_layer1(const float* __restrict__ g_in,
                                                const int* __restrict__ csr,
                                                const int* __restrict__ nnz_g,
                                                const float* __restrict__ dinv,
                                                const float* __restrict__ bias,
                                                const float* __restrict__ W,
                                                float* __restrict__ g_out,
                                                int2* __restrict__ edge) {
    __shared__ float sW[HID * HID];
    for (int i = threadIdx.x; i < HID * HID; i += 256) sW[i] = W[i];
    int wv = threadIdx.x >> 6, lane = threadIdx.x & 63;
    int row0 = swz32(blockIdx.x, wv);
    int bbase = row0 & ~(NN - 1);
    float bb = bias[lane];
    float h[RPW], o[RPW];
#pragma unroll
    for (int r = 0; r < RPW; ++r) {
        int row = row0 + r;
        int n = nnz_g[row];
        int idx = (lane < n) ? csr[row * CAP + lane] : 0;
        float dv = (lane < n) ? dinv[bbase + idx] : 0.f;
        if (lane < n) edge[row * CAP + lane] = make_int2(idx, __float_as_int(dv));
        h[r] = fmaxf(dinv[row] * spmm_row(g_in, bbase, n, idx, dv, lane) + bb, 0.f);
        o[r] = 0.f;
    }
    __syncthreads();
    for (int d = 0; d < HID; ++d) {
        float w = sW[d * HID + lane];
#pragma unroll
        for (int r = 0; r < RPW; ++r) o[r] += __shfl(h[r], d) * w;
    }
#pragma unroll
    for (int r = 0; r < RPW; ++r)
        g_out[(size_t)(row0 + r) * HID + lane] = o[r];
}

// ---------------- K3: layer2 — packed-edge SpMM + @W ------------------------
__global__ __launch_bounds__(256) void k_layer2(const float* __restrict__ g_in,
                                                const int2* __restrict__ edge,
                                                const int* __restrict__ nnz_g,
                                                const float* __restrict__ dinv,
                                                const float* __restrict__ bias,
                                                const float* __restrict__ W,
                                                float* __restrict__ g_out) {
    __shared__ float sW[HID * HID];
    for (int i = threadIdx.x; i < HID * HID; i += 256) sW[i] = W[i];
    int wv = threadIdx.x >> 6, lane = threadIdx.x & 63;
    int row0 = swz32(blockIdx.x, wv);
    int bbase = row0 & ~(NN - 1);
    float bb = bias[lane];
    float h[RPW], o[RPW];
#pragma unroll
    for (int r = 0; r < RPW; ++r) {
        int row = row0 + r;
        int n = nnz_g[row];
        int2 e = (lane < n) ? edge[row * CAP + lane] : make_int2(0, 0);
        float dv = __int_as_float(e.y);
        h[r] = fmaxf(dinv[row] * spmm_row(g_in, bbase, n, e.x, dv, lane) + bb, 0.f);
        o[r] = 0.f;
    }
    __syncthreads();
    for (int d = 0; d < HID; ++d) {
        float w = sW[d * HID + lane];
#pragma unroll
        for (int r = 0; r < RPW; ++r) o[r] += __shfl(h[r], d) * w;
    }
#pragma unroll
    for (int r = 0; r < RPW; ++r)
        g_out[(size_t)(row0 + r) * HID + lane] = o[r];
}

// ---------------- K4: layer3 — packed-edge SpMM + pool ----------------------
__global__ __launch_bounds__(256) void k_layer3(const float* __restrict__ g_in,
                                                const int2* __restrict__ edge,
                                                const int* __restrict__ nnz_g,
                                                const float* __restrict__ dinv,
                                                const float* __restrict__ bias,
                                                float* __restrict__ pooled) {
    __shared__ float sred[4][HID];
    int wv = threadIdx.x >> 6, lane = threadIdx.x & 63;
    int row0 = swz32(blockIdx.x, wv);
    int bbase = row0 & ~(NN - 1);
    float bb = bias[lane];
    float s = 0.f;
#pragma unroll
    for (int r = 0; r < RPW; ++r) {
        int row = row0 + r;
        int n = nnz_g[row];
        int2 e = (lane < n) ? edge[row * CAP + lane] : make_int2(0, 0);
        float dv = __int_as_float(e.y);
        s += fmaxf(dinv[row] * spmm_row(g_in, bbase, n, e.x, dv, lane) + bb, 0.f);
    }
    sred[wv][lane] = s;
    __syncthreads();
    if (wv == 0) {
        float tot = sred[0][lane] + sred[1][lane] + sred[2][lane] + sred[3][lane];
        atomicAdd(&pooled[(bbase >> 10) * HID + lane], tot);   // block = one batch
    }
}

// ---------------- K5: head ---------------------------------------------------
__global__ __launch_bounds__(128) void k_head(const float* __restrict__ pooled_sum,
                                              const float* __restrict__ Wf1,
                                              const float* __restrict__ bf1,
                                              const float* __restrict__ Wf2,
                                              const float* __restrict__ bf2,
                                              float* __restrict__ out) {
    int b = blockIdx.x, t = threadIdx.x;
    __shared__ float p[HID];
    __shared__ float hid[HEADD];
    if (t < HID) p[t] = pooled_sum[b * HID + t] * (1.0f / NN);
    __syncthreads();
    float acc = bf1[t];
    for (int d = 0; d < HID; ++d) acc += p[d] * Wf1[d * HEADD + t];
    hid[t] = fmaxf(acc, 0.f);
    __syncthreads();
    if (t < 64) {
        float v = hid[t] * Wf2[t] + hid[t + 64] * Wf2[t + 64];
#pragma unroll
        for (int off = 32; off > 0; off >>= 1) v += __shfl_down(v, off, 64);
        if (t == 0) out[b] = v + bf2[0];
    }
}

extern "C" void kernel_launch(void* const* d_in, const int* in_sizes, int n_in,
                              void* d_out, int out_size, void* d_ws, size_t ws_size,
                              hipStream_t stream) {
    const float* x   = (const float*)d_in[0];
    const float* adj = (const float*)d_in[1];
    const float* W1  = (const float*)d_in[2];
    const float* b1  = (const float*)d_in[3];
    const float* W2  = (const float*)d_in[4];
    const float* b2  = (const float*)d_in[5];
    const float* W3  = (const float*)d_in[6];
    const float* b3  = (const float*)d_in[7];
    const float* Wf1 = (const float*)d_in[8];
    const float* bf1 = (const float*)d_in[9];
    const float* Wf2 = (const float*)d_in[10];
    const float* bf2 = (const float*)d_in[11];
    float* out = (float*)d_out;

    // ws carve: csr 8MB | edge 16MB | nnz 128KB | dinv 128KB | pooled 16KB | g1,g2,g3 8MB
    char* ws = (char*)d_ws;
    size_t off = 0;
    int*   csr    = (int*)(ws + off);  off += (size_t)ROWS * CAP * 4;
    int2*  edge   = (int2*)(ws + off); off += (size_t)ROWS * CAP * 8;
    int*   nnz_g  = (int*)(ws + off);  off += (size_t)ROWS * 4;
    float* dinv   = (float*)(ws + off); off += (size_t)ROWS * 4;
    float* pooled = (float*)(ws + off); off += 4096 * 4;
    float* g1     = (float*)(ws + off); off += (size_t)ROWS * HID * 4;
    float* g2     = (float*)(ws + off); off += (size_t)ROWS * HID * 4;
    float* g3     = (float*)(ws + off);

    k_build <<<ROWS / 4, 256, 0, stream>>>(adj, x, W1, csr, nnz_g, dinv, g1, pooled);
    k_layer1<<<ROWS / 32, 256, 0, stream>>>(g1, csr, nnz_g, dinv, b1, W2, g2, edge);
    k_layer2<<<ROWS / 32, 256, 0, stream>>>(g2, edge, nnz_g, dinv, b2, W3, g3);
    k_layer3<<<ROWS / 32, 256, 0, stream>>>(g3, edge, nnz_g, dinv, b3, pooled);
    k_head  <<<BATCH, 128, 0, stream>>>(pooled, Wf1, bf1, Wf2, bf2, out);
}

// Round 8
// 301.374 us; speedup vs baseline: 2.8095x; 1.0989x over previous
//
#include <hip/hip_runtime.h>
#include <math.h>

#define NN 1024
#define HID 64
#define HEADD 128
#define NODE_DIM 14
#define BATCH 32
#define CAP 64
#define ROWS (BATCH * NN)   // 32768
#define RPW 8               // rows per wave in layer kernels

// ---- swizzles -------------------------------------------------------------
__device__ __forceinline__ int swz4(int blk, int wv) {
    int x = blk & 7, q = blk >> 3;
    int batch = x + 8 * (q >> 8);
    return batch * NN + ((q & 255) << 2) + wv;
}
__device__ __forceinline__ int swz32(int blk, int wv) {
    int x = blk & 7, q = blk >> 3;          // q in [0,128)
    int batch = x + 8 * (q >> 5);
    return batch * NN + ((q & 31) << 5) + wv * RPW;
}

__device__ __forceinline__ float rl_f(float v, int k) {
    return __int_as_float(__builtin_amdgcn_readlane(__float_as_int(v), k));
}

// ---------------- K1: CSR build (ballot) + g1 = x @ W1 + zero pooled --------
__global__ __launch_bounds__(256) void k_build(const float* __restrict__ adj,
                                               const float* __restrict__ x,
                                               const float* __restrict__ W1,
                                               int* __restrict__ csr,
                                               int* __restrict__ nnz_g,
                                               float* __restrict__ dinv,
                                               float* __restrict__ g1,
                                               float* __restrict__ pooled) {
    __shared__ float sW1[NODE_DIM * HID];
    for (int i = threadIdx.x; i < NODE_DIM * HID; i += 256) sW1[i] = W1[i];
    if (blockIdx.x < 8) pooled[blockIdx.x * 256 + threadIdx.x] = 0.f;
    int wv = threadIdx.x >> 6, lane = threadIdx.x & 63;
    int row = swz4(blockIdx.x, wv);
    const float4* rp = reinterpret_cast<const float4*>(adj + (size_t)row * NN);
    unsigned long long lt = ((unsigned long long)1 << lane) - 1;
    int base = 0;
#pragma unroll
    for (int j = 0; j < 4; ++j) {
        float4 v = rp[lane + 64 * j];
        float vv[4] = {v.x, v.y, v.z, v.w};
#pragma unroll
        for (int k = 0; k < 4; ++k) {
            unsigned long long mk = __ballot(vv[k] != 0.0f);
            if (vv[k] != 0.0f) {
                int pos = base + __popcll(mk & lt);
                if (pos < CAP) csr[row * CAP + pos] = (lane + 64 * j) * 4 + k;
            }
            base += __popcll(mk);
        }
    }
    if (lane == 0) {
        nnz_g[row] = base < CAP ? base : CAP;
        dinv[row] = 1.0f / sqrtf((float)(base < 1 ? 1 : base));
    }
    __syncthreads();
    float acc = 0.f;
    const float* xr = x + (size_t)row * NODE_DIM;
#pragma unroll
    for (int d = 0; d < NODE_DIM; ++d) acc += xr[d] * sW1[d * HID + lane];
    g1[(size_t)row * HID + lane] = acc;
}

// Gather-SpMM for one row via readlane broadcast (VALU, no LDS pipe).
// n must be wave-uniform (readfirstlane'd by caller). Sequential-k sum order.
__device__ __forceinline__ float spmm_row(const float* __restrict__ g_in,
                                          int bbase, int n, int idx, float dv,
                                          int lane) {
    float acc = 0.f;
    int k = 0;
    for (; k + 4 <= n; k += 4) {
        int j0 = __builtin_amdgcn_readlane(idx, k);
        int j1 = __builtin_amdgcn_readlane(idx, k + 1);
        int j2 = __builtin_amdgcn_readlane(idx, k + 2);
        int j3 = __builtin_amdgcn_readlane(idx, k + 3);
        float w0 = rl_f(dv, k),     w1 = rl_f(dv, k + 1);
        float w2 = rl_f(dv, k + 2), w3 = rl_f(dv, k + 3);
        float v0 = g_in[(size_t)(bbase + j0) * HID + lane];
        float v1 = g_in[(size_t)(bbase + j1) * HID + lane];
        float v2 = g_in[(size_t)(bbase + j2) * HID + lane];
        float v3 = g_in[(size_t)(bbase + j3) * HID + lane];
        acc += w0 * v0; acc += w1 * v1; acc += w2 * v2; acc += w3 * v3;
    }
    for (; k < n; ++k) {
        int j = __builtin_amdgcn_readlane(idx, k);
        acc += rl_f(dv, k) * g_in[(size_t)(bbase + j) * HID + lane];
    }
    return acc;
}

// Register-resident W GEMM: o[r] = sum_d readlane(h[r],d) * wreg[d].
// readlane(const d) -> SGPR; v_fmac with 1 SGPR operand. No LDS at all.
__device__ __forceinline__ void gemm_rows(const float h[RPW], const float wreg[HID],
                                          float o[RPW]) {
#pragma unroll
    for (int r = 0; r < RPW; ++r) o[r] = 0.f;
#pragma unroll
    for (int d = 0; d < HID; ++d) {
        float w = wreg[d];
#pragma unroll
        for (int r = 0; r < RPW; ++r) o[r] += rl_f(h[r], d) * w;
    }
}

// ---------------- K2: layer1 — csr+dinv gather, EMITS packed edges ----------
__global__ __launch_bounds__(256, 4) void k_layer1(const float* __restrict__ g_in,
                                                   const int* __restrict__ csr,
                                                   const int* __restrict__ nnz_g,
                                                   const float* __restrict__ dinv,
                                                   const float* __restrict__ bias,
                                                   const float* __restrict__ W,
                                                   float* __restrict__ g_out,
                                                   int2* __restrict__ edge) {
    int wv = threadIdx.x >> 6, lane = threadIdx.x & 63;
    float wreg[HID];
#pragma unroll
    for (int d = 0; d < HID; ++d) wreg[d] = W[d * HID + lane];
    int row0 = swz32(blockIdx.x, wv);
    int bbase = row0 & ~(NN - 1);
    float bb = bias[lane];
    float h[RPW];
#pragma unroll
    for (int r = 0; r < RPW; ++r) {
        int row = row0 + r;
        int n = __builtin_amdgcn_readfirstlane(nnz_g[row]);
        int idx = (lane < n) ? csr[row * CAP + lane] : 0;
        float dv = (lane < n) ? dinv[bbase + idx] : 0.f;
        if (lane < n) edge[row * CAP + lane] = make_int2(idx, __float_as_int(dv));
        h[r] = fmaxf(dinv[row] * spmm_row(g_in, bbase, n, idx, dv, lane) + bb, 0.f);
    }
    float o[RPW];
    gemm_rows(h, wreg, o);
#pragma unroll
    for (int r = 0; r < RPW; ++r)
        g_out[(size_t)(row0 + r) * HID + lane] = o[r];
}

// ---------------- K3: layer2 — packed-edge SpMM + register GEMM -------------
__global__ __launch_bounds__(256, 4) void k_layer2(const float* __restrict__ g_in,
                                                   const int2* __restrict__ edge,
                                                   const int* __restrict__ nnz_g,
                                                   const float* __restrict__ dinv,
                                                   const float* __restrict__ bias,
                                                   const float* __restrict__ W,
                                                   float* __restrict__ g_out) {
    int wv = threadIdx.x >> 6, lane = threadIdx.x & 63;
    float wreg[HID];
#pragma unroll
    for (int d = 0; d < HID; ++d) wreg[d] = W[d * HID + lane];
    int row0 = swz32(blockIdx.x, wv);
    int bbase = row0 & ~(NN - 1);
    float bb = bias[lane];
    float h[RPW];
#pragma unroll
    for (int r = 0; r < RPW; ++r) {
        int row = row0 + r;
        int n = __builtin_amdgcn_readfirstlane(nnz_g[row]);
        int2 e = (lane < n) ? edge[row * CAP + lane] : make_int2(0, 0);
        float dv = __int_as_float(e.y);
        h[r] = fmaxf(dinv[row] * spmm_row(g_in, bbase, n, e.x, dv, lane) + bb, 0.f);
    }
    float o[RPW];
    gemm_rows(h, wreg, o);
#pragma unroll
    for (int r = 0; r < RPW; ++r)
        g_out[(size_t)(row0 + r) * HID + lane] = o[r];
}

// ---------------- K4: layer3 — packed-edge SpMM + pool ----------------------
__global__ __launch_bounds__(256, 4) void k_layer3(const float* __restrict__ g_in,
                                                   const int2* __restrict__ edge,
                                                   const int* __restrict__ nnz_g,
                                                   const float* __restrict__ dinv,
                                                   const float* __restrict__ bias,
                                                   float* __restrict__ pooled) {
    __shared__ float sred[4][HID];
    int wv = threadIdx.x >> 6, lane = threadIdx.x & 63;
    int row0 = swz32(blockIdx.x, wv);
    int bbase = row0 & ~(NN - 1);
    float bb = bias[lane];
    float s = 0.f;
#pragma unroll
    for (int r = 0; r < RPW; ++r) {
        int row = row0 + r;
        int n = __builtin_amdgcn_readfirstlane(nnz_g[row]);
        int2 e = (lane < n) ? edge[row * CAP + lane] : make_int2(0, 0);
        float dv = __int_as_float(e.y);
        s += fmaxf(dinv[row] * spmm_row(g_in, bbase, n, e.x, dv, lane) + bb, 0.f);
    }
    sred[wv][lane] = s;
    __syncthreads();
    if (wv == 0) {
        float tot = sred[0][lane] + sred[1][lane] + sred[2][lane] + sred[3][lane];
        atomicAdd(&pooled[(bbase >> 10) * HID + lane], tot);
    }
}

// ---------------- K5: head ---------------------------------------------------
__global__ __launch_bounds__(128) void k_head(const float* __restrict__ pooled_sum,
                                              const float* __restrict__ Wf1,
                                              const float* __restrict__ bf1,
                                              const float* __restrict__ Wf2,
                                              const float* __restrict__ bf2,
                                              float* __restrict__ out) {
    int b = blockIdx.x, t = threadIdx.x;
    __shared__ float p[HID];
    __shared__ float hid[HEADD];
    if (t < HID) p[t] = pooled_sum[b * HID + t] * (1.0f / NN);
    __syncthreads();
    float acc = bf1[t];
    for (int d = 0; d < HID; ++d) acc += p[d] * Wf1[d * HEADD + t];
    hid[t] = fmaxf(acc, 0.f);
    __syncthreads();
    if (t < 64) {
        float v = hid[t] * Wf2[t] + hid[t + 64] * Wf2[t + 64];
#pragma unroll
        for (int off = 32; off > 0; off >>= 1) v += __shfl_down(v, off, 64);
        if (t == 0) out[b] = v + bf2[0];
    }
}

extern "C" void kernel_launch(void* const* d_in, const int* in_sizes, int n_in,
                              void* d_out, int out_size, void* d_ws, size_t ws_size,
                              hipStream_t stream) {
    const float* x   = (const float*)d_in[0];
    const float* adj = (const float*)d_in[1];
    const float* W1  = (const float*)d_in[2];
    const float* b1  = (const float*)d_in[3];
    const float* W2  = (const float*)d_in[4];
    const float* b2  = (const float*)d_in[5];
    const float* W3  = (const float*)d_in[6];
    const float* b3  = (const float*)d_in[7];
    const float* Wf1 = (const float*)d_in[8];
    const float* bf1 = (const float*)d_in[9];
    const float* Wf2 = (const float*)d_in[10];
    const float* bf2 = (const float*)d_in[11];
    float* out = (float*)d_out;

    char* ws = (char*)d_ws;
    size_t off = 0;
    int*   csr    = (int*)(ws + off);   off += (size_t)ROWS * CAP * 4;
    int2*  edge   = (int2*)(ws + off);  off += (size_t)ROWS * CAP * 8;
    int*   nnz_g  = (int*)(ws + off);   off += (size_t)ROWS * 4;
    float* dinv   = (float*)(ws + off); off += (size_t)ROWS * 4;
    float* pooled = (float*)(ws + off); off += 4096 * 4;
    float* g1     = (float*)(ws + off); off += (size_t)ROWS * HID * 4;
    float* g2     = (float*)(ws + off); off += (size_t)ROWS * HID * 4;
    float* g3     = (float*)(ws + off);

    k_build <<<ROWS / 4, 256, 0, stream>>>(adj, x, W1, csr, nnz_g, dinv, g1, pooled);
    k_layer1<<<ROWS / 32, 256, 0, stream>>>(g1, csr, nnz_g, dinv, b1, W2, g2, edge);
    k_layer2<<<ROWS / 32, 256, 0, stream>>>(g2, edge, nnz_g, dinv, b2, W3, g3);
    k_layer3<<<ROWS / 32, 256, 0, stream>>>(g3, edge, nnz_g, dinv, b3, pooled);
    k_head  <<<BATCH, 128, 0, stream>>>(pooled, Wf1, bf1, Wf2, bf2, out);
}

// Round 9
// 293.589 us; speedup vs baseline: 2.8840x; 1.0265x over previous
//
#include <hip/hip_runtime.h>
#include <math.h>

#define NN 1024
#define HID 64
#define HEADD 128
#define NODE_DIM 14
#define BATCH 32
#define CAP 64
#define ROWS (BATCH * NN)   // 32768
#define RPW 8               // rows per wave in layer kernels

// ---- swizzles (XCD-aware: blk%8 pins a batch's slab to one XCD L2) --------
__device__ __forceinline__ int swz4(int blk, int wv) {
    int x = blk & 7, q = blk >> 3;
    int batch = x + 8 * (q >> 8);
    return batch * NN + ((q & 255) << 2) + wv;
}
__device__ __forceinline__ int swz32(int blk, int wv) {
    int x = blk & 7, q = blk >> 3;          // q in [0,128)
    int batch = x + 8 * (q >> 5);
    return batch * NN + ((q & 31) << 5) + wv * RPW;
}

__device__ __forceinline__ float rl_f(float v, int k) {
    return __int_as_float(__builtin_amdgcn_readlane(__float_as_int(v), k));
}

// ---------------- K1: CSR build (ballot) + g1 = x @ W1 + zero pooled --------
__global__ __launch_bounds__(256) void k_build(const float* __restrict__ adj,
                                               const float* __restrict__ x,
                                               const float* __restrict__ W1,
                                               unsigned short* __restrict__ csr,
                                               int* __restrict__ nnz_g,
                                               float* __restrict__ dinv,
                                               float* __restrict__ g1,
                                               float* __restrict__ pooled) {
    __shared__ float sW1[NODE_DIM * HID];
    for (int i = threadIdx.x; i < NODE_DIM * HID; i += 256) sW1[i] = W1[i];
    if (blockIdx.x < 8) pooled[blockIdx.x * 256 + threadIdx.x] = 0.f;
    int wv = threadIdx.x >> 6, lane = threadIdx.x & 63;
    int row = swz4(blockIdx.x, wv);
    const float4* rp = reinterpret_cast<const float4*>(adj + (size_t)row * NN);
    unsigned long long lt = ((unsigned long long)1 << lane) - 1;
    int base = 0;
#pragma unroll
    for (int j = 0; j < 4; ++j) {
        float4 v = rp[lane + 64 * j];
        float vv[4] = {v.x, v.y, v.z, v.w};
#pragma unroll
        for (int k = 0; k < 4; ++k) {
            unsigned long long mk = __ballot(vv[k] != 0.0f);
            if (mk) {                         // wave-uniform: skip empty masks (~53%)
                if (vv[k] != 0.0f) {
                    int pos = base + __popcll(mk & lt);
                    if (pos < CAP)
                        csr[row * CAP + pos] = (unsigned short)((lane + 64 * j) * 4 + k);
                }
                base += __popcll(mk);
            }
        }
    }
    if (lane == 0) {
        nnz_g[row] = base < CAP ? base : CAP;
        dinv[row] = 1.0f / sqrtf((float)(base < 1 ? 1 : base));
    }
    __syncthreads();
    float acc = 0.f;
    const float* xr = x + (size_t)row * NODE_DIM;
#pragma unroll
    for (int d = 0; d < NODE_DIM; ++d) acc += xr[d] * sW1[d * HID + lane];
    g1[(size_t)row * HID + lane] = acc;
}

// 8-row interleaved SpMM: per k-step, 8 independent gathers in flight.
// dv lanes >= n[r] are zero, so k >= n[r] contributes exactly +0.0 (branch-free).
__device__ __forceinline__ void spmm8(const float* __restrict__ g_in,
                                      int bbase, const int n[RPW],
                                      const int idx[RPW], const float dv[RPW],
                                      int lane, float acc[RPW]) {
    int nmax = 0;
#pragma unroll
    for (int r = 0; r < RPW; ++r) { acc[r] = 0.f; nmax = n[r] > nmax ? n[r] : nmax; }
    for (int k = 0; k < nmax; ++k) {
        float w[RPW], v[RPW];
#pragma unroll
        for (int r = 0; r < RPW; ++r) {
            int j = __builtin_amdgcn_readlane(idx[r], k);
            w[r] = rl_f(dv[r], k);
            v[r] = g_in[(bbase + j) * HID + lane];
        }
#pragma unroll
        for (int r = 0; r < RPW; ++r) acc[r] += w[r] * v[r];
    }
}

// ---------------- K2/K3: g_out = relu(D A D g_in + bias) @ W ----------------
__global__ __launch_bounds__(256, 4) void k_layer(const float* __restrict__ g_in,
                                                  const unsigned short* __restrict__ csr,
                                                  const int* __restrict__ nnz_g,
                                                  const float* __restrict__ dinv,
                                                  const float* __restrict__ bias,
                                                  const float* __restrict__ W,
                                                  float* __restrict__ g_out) {
    int wv = threadIdx.x >> 6, lane = threadIdx.x & 63;
    float wreg[HID];
#pragma unroll
    for (int d = 0; d < HID; ++d) wreg[d] = W[d * HID + lane];
    int row0 = swz32(blockIdx.x, wv);
    int bbase = row0 & ~(NN - 1);
    float bb = bias[lane];
    int n[RPW], idx[RPW];
    float dv[RPW];
#pragma unroll
    for (int r = 0; r < RPW; ++r) {
        int row = row0 + r;
        n[r] = __builtin_amdgcn_readfirstlane(nnz_g[row]);
        idx[r] = (lane < n[r]) ? (int)csr[row * CAP + lane] : 0;
        dv[r] = (lane < n[r]) ? dinv[bbase + idx[r]] : 0.f;
    }
    float acc[RPW];
    spmm8(g_in, bbase, n, idx, dv, lane, acc);
    float h[RPW];
#pragma unroll
    for (int r = 0; r < RPW; ++r)
        h[r] = fmaxf(dinv[row0 + r] * acc[r] + bb, 0.f);
    float o[RPW];
#pragma unroll
    for (int r = 0; r < RPW; ++r) o[r] = 0.f;
#pragma unroll
    for (int d = 0; d < HID; ++d) {
        float w = wreg[d];
#pragma unroll
        for (int r = 0; r < RPW; ++r) o[r] += rl_f(h[r], d) * w;
    }
#pragma unroll
    for (int r = 0; r < RPW; ++r)
        g_out[(size_t)(row0 + r) * HID + lane] = o[r];
}

// ---------------- K4: h3 = relu(DAD g3 + b3); pool --------------------------
__global__ __launch_bounds__(256, 4) void k_layer3(const float* __restrict__ g_in,
                                                   const unsigned short* __restrict__ csr,
                                                   const int* __restrict__ nnz_g,
                                                   const float* __restrict__ dinv,
                                                   const float* __restrict__ bias,
                                                   float* __restrict__ pooled) {
    __shared__ float sred[4][HID];
    int wv = threadIdx.x >> 6, lane = threadIdx.x & 63;
    int row0 = swz32(blockIdx.x, wv);
    int bbase = row0 & ~(NN - 1);
    float bb = bias[lane];
    int n[RPW], idx[RPW];
    float dv[RPW];
#pragma unroll
    for (int r = 0; r < RPW; ++r) {
        int row = row0 + r;
        n[r] = __builtin_amdgcn_readfirstlane(nnz_g[row]);
        idx[r] = (lane < n[r]) ? (int)csr[row * CAP + lane] : 0;
        dv[r] = (lane < n[r]) ? dinv[bbase + idx[r]] : 0.f;
    }
    float acc[RPW];
    spmm8(g_in, bbase, n, idx, dv, lane, acc);
    float s = 0.f;
#pragma unroll
    for (int r = 0; r < RPW; ++r)
        s += fmaxf(dinv[row0 + r] * acc[r] + bb, 0.f);
    sred[wv][lane] = s;
    __syncthreads();
    if (wv == 0) {
        float tot = sred[0][lane] + sred[1][lane] + sred[2][lane] + sred[3][lane];
        atomicAdd(&pooled[(bbase >> 10) * HID + lane], tot);
    }
}

// ---------------- K5: head ---------------------------------------------------
__global__ __launch_bounds__(128) void k_head(const float* __restrict__ pooled_sum,
                                              const float* __restrict__ Wf1,
                                              const float* __restrict__ bf1,
                                              const float* __restrict__ Wf2,
                                              const float* __restrict__ bf2,
                                              float* __restrict__ out) {
    int b = blockIdx.x, t = threadIdx.x;
    __shared__ float p[HID];
    __shared__ float hid[HEADD];
    if (t < HID) p[t] = pooled_sum[b * HID + t] * (1.0f / NN);
    __syncthreads();
    float acc = bf1[t];
    for (int d = 0; d < HID; ++d) acc += p[d] * Wf1[d * HEADD + t];
    hid[t] = fmaxf(acc, 0.f);
    __syncthreads();
    if (t < 64) {
        float v = hid[t] * Wf2[t] + hid[t + 64] * Wf2[t + 64];
#pragma unroll
        for (int off = 32; off > 0; off >>= 1) v += __shfl_down(v, off, 64);
        if (t == 0) out[b] = v + bf2[0];
    }
}

extern "C" void kernel_launch(void* const* d_in, const int* in_sizes, int n_in,
                              void* d_out, int out_size, void* d_ws, size_t ws_size,
                              hipStream_t stream) {
    const float* x   = (const float*)d_in[0];
    const float* adj = (const float*)d_in[1];
    const float* W1  = (const float*)d_in[2];
    const float* b1  = (const float*)d_in[3];
    const float* W2  = (const float*)d_in[4];
    const float* b2  = (const float*)d_in[5];
    const float* W3  = (const float*)d_in[6];
    const float* b3  = (const float*)d_in[7];
    const float* Wf1 = (const float*)d_in[8];
    const float* bf1 = (const float*)d_in[9];
    const float* Wf2 = (const float*)d_in[10];
    const float* bf2 = (const float*)d_in[11];
    float* out = (float*)d_out;

    // ws carve: csr(ushort) 4MB | nnz 128KB | dinv 128KB | pooled 16KB | g1,g2,g3 8MB
    char* ws = (char*)d_ws;
    size_t off = 0;
    unsigned short* csr = (unsigned short*)(ws + off); off += (size_t)ROWS * CAP * 2;
    int*   nnz_g  = (int*)(ws + off);   off += (size_t)ROWS * 4;
    float* dinv   = (float*)(ws + off); off += (size_t)ROWS * 4;
    float* pooled = (float*)(ws + off); off += 4096 * 4;
    float* g1     = (float*)(ws + off); off += (size_t)ROWS * HID * 4;
    float* g2     = (float*)(ws + off); off += (size_t)ROWS * HID * 4;
    float* g3     = (float*)(ws + off);

    k_build <<<ROWS / 4, 256, 0, stream>>>(adj, x, W1, csr, nnz_g, dinv, g1, pooled);
    k_layer <<<ROWS / 32, 256, 0, stream>>>(g1, csr, nnz_g, dinv, b1, W2, g2);
    k_layer <<<ROWS / 32, 256, 0, stream>>>(g2, csr, nnz_g, dinv, b2, W3, g3);
    k_layer3<<<ROWS / 32, 256, 0, stream>>>(g3, csr, nnz_g, dinv, b3, pooled);
    k_head  <<<BATCH, 128, 0, stream>>>(pooled, Wf1, bf1, Wf2, bf2, out);
}